// Round 4
// baseline (169.922 us; speedup 1.0000x reference)
//
#include <hip/hip_runtime.h>
#include <hip/hip_bf16.h>
#include <cstdint>

#define B_ 2
#define S_ 2048
#define D_ 1024
#define H_ 16
#define HD_ 64
#define M_ (B_*S_)   // 4096

#define LOG2E 1.4426950408889634f
#define C1_ (0.125f * LOG2E)   // 1/sqrt(64) * log2(e), folded into Q at GEMM epilogue

typedef unsigned short u16;
typedef __bf16 bf16x8 __attribute__((ext_vector_type(8)));
typedef u16 u16x8 __attribute__((ext_vector_type(8)));
typedef float f32x4 __attribute__((ext_vector_type(4)));
typedef float f32x16 __attribute__((ext_vector_type(16)));
typedef int i32x4 __attribute__((ext_vector_type(4)));

static __device__ __forceinline__ u16 f2bu(float f) {
  __bf16 b = (__bf16)f;
  return __builtin_bit_cast(unsigned short, b);
}

static __device__ __forceinline__ int cvtpk(float a, float b) {
  int r;
  asm("v_cvt_pk_bf16_f32 %0, %1, %2" : "=v"(r) : "v"(a), "v"(b));
  return r;
}
static __device__ __forceinline__ void plswap(int &x, int &y) {
  asm("v_permlane32_swap_b32 %0, %1" : "+v"(x), "+v"(y));
}

#define GLOAD16(g, l) __builtin_amdgcn_global_load_lds( \
    (__attribute__((address_space(1))) void*)(g), \
    (__attribute__((address_space(3))) void*)(l), 16, 0, 0)

// ---------------- LayerNorm: fp32 [4096][1024] -> bf16 h ----------------
__global__ __launch_bounds__(256) void ln_kernel(const float* __restrict__ x,
    const float* __restrict__ g, const float* __restrict__ be, u16* __restrict__ h) {
  const int row = blockIdx.x;
  const int t = threadIdx.x;
  float4 v = reinterpret_cast<const float4*>(x + (size_t)row * D_)[t];
  float s = v.x + v.y + v.z + v.w;
  float sq = v.x*v.x + v.y*v.y + v.z*v.z + v.w*v.w;
  #pragma unroll
  for (int off = 32; off >= 1; off >>= 1) {
    s  += __shfl_down(s, off);
    sq += __shfl_down(sq, off);
  }
  __shared__ float red[8];
  const int wave = t >> 6, lane = t & 63;
  if (lane == 0) { red[wave] = s; red[4 + wave] = sq; }
  __syncthreads();
  if (t == 0) {
    float ts = red[0]+red[1]+red[2]+red[3];
    float tq = red[4]+red[5]+red[6]+red[7];
    float mu = ts * (1.0f / D_);
    red[0] = mu;
    red[1] = rsqrtf(tq * (1.0f / D_) - mu*mu + 1e-5f);
  }
  __syncthreads();
  const float mu = red[0], rs = red[1];
  float4 gg = reinterpret_cast<const float4*>(g)[t];
  float4 bb = reinterpret_cast<const float4*>(be)[t];
  ushort4 o;
  o.x = f2bu((v.x - mu) * rs * gg.x + bb.x);
  o.y = f2bu((v.y - mu) * rs * gg.y + bb.y);
  o.z = f2bu((v.z - mu) * rs * gg.z + bb.z);
  o.w = f2bu((v.w - mu) * rs * gg.w + bb.w);
  reinterpret_cast<ushort4*>(h + (size_t)row * D_)[t] = o;
}

// ------------- Weight transpose+convert: W[k][n] fp32 -> Wt[n][k] bf16 -------------
__global__ __launch_bounds__(256) void wt_kernel(const float* __restrict__ W0,
    const float* __restrict__ W1, const float* __restrict__ W2, u16* __restrict__ wt) {
  const int z = blockIdx.z;
  const float* W = (z == 0) ? W0 : ((z == 1) ? W1 : W2);
  u16* out = wt + (size_t)z * D_ * D_;
  __shared__ float tile[32][33];
  const int n0 = blockIdx.x * 32, k0 = blockIdx.y * 32;
  const int tx = threadIdx.x, ty = threadIdx.y;
  #pragma unroll
  for (int j = 0; j < 4; ++j)
    tile[ty + 8*j][tx] = W[(size_t)(k0 + ty + 8*j) * D_ + n0 + tx];
  __syncthreads();
  #pragma unroll
  for (int j = 0; j < 4; ++j)
    out[(size_t)(n0 + ty + 8*j) * D_ + k0 + tx] = f2bu(tile[tx][ty + 8*j]);
}

// ------------- QKV GEMM: 128x128 tile, BK=32, T2-swizzled LDS -------------
// Q scaled by C1_ and stored [B,H,S,HD]; K [B,H,S,HD]; V TRANSPOSED [B,H,HD,S].
__global__ __launch_bounds__(256) void qkv_gemm(const u16* __restrict__ hbuf,
    const u16* __restrict__ wt, u16* __restrict__ qkv) {
  const int z = blockIdx.z;
  const u16* Bt = wt + (size_t)z * D_ * D_;
  u16* outp = qkv + (size_t)z * (B_*H_*S_*HD_);
  __shared__ __align__(16) u16 As[128 * 32];
  __shared__ __align__(16) u16 Bs[128 * 32];
  const int t = threadIdx.x, lane = t & 63, wave = t >> 6;
  const int row0 = blockIdx.y * 128, col0 = blockIdx.x * 128;
  const int wm = wave >> 1, wn = wave & 1;
  f32x4 acc[4][4] = {};
  const int schunk = (t & 3) ^ ((t >> 3) & 3);
  const u16* ag = hbuf + (size_t)(row0 + (t >> 2)) * D_ + schunk * 8;
  const u16* bg = Bt   + (size_t)(col0 + (t >> 2)) * D_ + schunk * 8;
  u16* lA = &As[wave * 512];
  u16* lB = &Bs[wave * 512];
  const char* Ac = (const char*)As;
  const char* Bc = (const char*)Bs;
  const int cbase = (((lane >> 4) ^ ((lane >> 1) & 3)) << 4);

  for (int k0 = 0; k0 < D_; k0 += 32) {
    GLOAD16(ag + k0,           lA);
    GLOAD16(ag + k0 + 64 * D_, lA + 2048);
    GLOAD16(bg + k0,           lB);
    GLOAD16(bg + k0 + 64 * D_, lB + 2048);
    __syncthreads();
    bf16x8 af[4], bfr[4];
    #pragma unroll
    for (int m = 0; m < 4; ++m)
      af[m] = *reinterpret_cast<const bf16x8*>(Ac + (wm*64 + m*16 + (lane & 15)) * 64 + cbase);
    #pragma unroll
    for (int n = 0; n < 4; ++n)
      bfr[n] = *reinterpret_cast<const bf16x8*>(Bc + (wn*64 + n*16 + (lane & 15)) * 64 + cbase);
    #pragma unroll
    for (int m = 0; m < 4; ++m) {
      #pragma unroll
      for (int n = 0; n < 4; ++n)
        acc[m][n] = __builtin_amdgcn_mfma_f32_16x16x32_bf16(af[m], bfr[n], acc[m][n], 0, 0, 0);
    }
    __syncthreads();
  }
  const float scl = (z == 0) ? C1_ : 1.0f;   // fold 1/sqrt(d)*log2e into Q
  #pragma unroll
  for (int m = 0; m < 4; ++m) {
    #pragma unroll
    for (int n = 0; n < 4; ++n) {
      const int gcol = col0 + wn*64 + n*16 + (lane & 15);
      const int hI = gcol >> 6, dI = gcol & 63;
      #pragma unroll
      for (int r = 0; r < 4; ++r) {
        const int grow = row0 + wm*64 + m*16 + (lane >> 4) * 4 + r;
        const int bI = grow >> 11, sI = grow & (S_ - 1);
        size_t idx;
        if (z == 2) idx = ((size_t)(bI * H_ + hI) * HD_ + dI) * S_ + sI;   // V transposed
        else        idx = ((size_t)(bI * H_ + hI) * S_ + sI) * HD_ + dI;
        outp[idx] = f2bu(acc[m][n][r] * scl);
      }
    }
  }
}

// ---- softmax + pack; defer-max, NO hot-path cross-lane ops ----
static __device__ __forceinline__ void sm_pack(
    const f32x16& s, const float4* __restrict__ mk,
    float& dm, float& lsum, f32x16& o0, f32x16& o1,
    bf16x8& pfA, bf16x8& pfB) {
  float zb[16];
  #pragma unroll
  for (int r = 0; r < 4; ++r) {
    zb[r]      = s[r]      + ((const float*)&mk[0])[r];
    zb[r + 4]  = s[r + 4]  + ((const float*)&mk[1])[r];
    zb[r + 8]  = s[r + 8]  + ((const float*)&mk[2])[r];
    zb[r + 12] = s[r + 12] + ((const float*)&mk[3])[r];
  }
  // lane-local guard max (tree; no shuffle on hot path)
  float a0 = fmaxf(fmaxf(zb[0], zb[1]), zb[2]);
  float a1 = fmaxf(fmaxf(zb[3], zb[4]), zb[5]);
  float a2 = fmaxf(fmaxf(zb[6], zb[7]), zb[8]);
  float a3 = fmaxf(fmaxf(zb[9], zb[10]), zb[11]);
  float a4 = fmaxf(fmaxf(zb[12], zb[13]), zb[14]);
  float tm = fmaxf(fmaxf(fmaxf(a0, a1), fmaxf(a2, a3)), fmaxf(a4, zb[15]));
  if (__builtin_expect(__any(tm > dm + 8.0f), 0)) {   // cold rescale
    float tp = fmaxf(tm, __shfl_xor(tm, 32));         // q-row pair max
    float dnew = fmaxf(dm, tp - 8.0f);
    float sf = __builtin_amdgcn_exp2f(dm - dnew);
    lsum *= sf; o0 = o0 * sf; o1 = o1 * sf; dm = dnew;
  }
  float p[16];
  #pragma unroll
  for (int r = 0; r < 16; ++r) p[r] = __builtin_amdgcn_exp2f(zb[r] - dm);
  float s01 = (p[0] + p[1]) + (p[2] + p[3]);
  float s23 = (p[4] + p[5]) + (p[6] + p[7]);
  float s45 = (p[8] + p[9]) + (p[10] + p[11]);
  float s67 = (p[12] + p[13]) + (p[14] + p[15]);
  lsum += (s01 + s23) + (s45 + s67);   // lane-local; cross-half deferred to epilogue
  int pk01 = cvtpk(p[0], p[1]),   pk23 = cvtpk(p[2], p[3]);
  int pk45 = cvtpk(p[4], p[5]),   pk67 = cvtpk(p[6], p[7]);
  int pk89 = cvtpk(p[8], p[9]),   pkAB = cvtpk(p[10], p[11]);
  int pkCD = cvtpk(p[12], p[13]), pkEF = cvtpk(p[14], p[15]);
  plswap(pk01, pk45); plswap(pk23, pk67);
  plswap(pk89, pkCD); plswap(pkAB, pkEF);
  i32x4 c0 = {pk01, pk23, pk45, pk67};
  i32x4 c1 = {pk89, pkAB, pkCD, pkEF};
  pfA = __builtin_bit_cast(bf16x8, c0);
  pfB = __builtin_bit_cast(bf16x8, c1);
}

// ------------- Flash attention: NO K/V LDS (L2-resident), no main-loop barriers -------------
// 4 waves x 32 q per block; K-frags ping-pong prefetched from global; V-frags issued at tile top.
__global__ __launch_bounds__(256, 2) void attn_kernel(const u16* __restrict__ qkv,
    const float* __restrict__ mask, float* __restrict__ out) {
  const int bid = blockIdx.x;
  // bijective XCD map: plane p -> XCD (p&7); 4 planes (2MB K+V) per XCD L2
  const int x = bid & 7, rr = bid >> 3;
  const int j = rr & 15;                    // q-tile (128 q)
  const int pidx = x + ((rr >> 4) << 3);    // plane 0..31 = b*16+h
  const int hI = pidx & 15, bI = pidx >> 4;
  const size_t plane = (size_t)pidx * (S_ * HD_);
  const u16* Qp  = qkv + plane;
  const u16* Kp  = qkv + (size_t)(B_*H_*S_*HD_) + plane;
  const u16* Vtp = qkv + 2*(size_t)(B_*H_*S_*HD_) + plane;   // [d][s]

  const int t = threadIdx.x, lane = t & 63, wave = t >> 6;
  const int cl = lane & 31, hf = lane >> 5;

  __shared__ float maskLds[S_];
  #pragma unroll
  for (int i = 0; i < 2; ++i) {
    float4 mv = reinterpret_cast<const float4*>(mask + (size_t)bI * S_)[t + i*256];
    float4 sm = {mv.x * LOG2E - 8.0f, mv.y * LOG2E - 8.0f,
                 mv.z * LOG2E - 8.0f, mv.w * LOG2E - 8.0f};
    reinterpret_cast<float4*>(maskLds)[t + i*256] = sm;
  }

  const int q0 = j * 128 + wave * 32;
  bf16x8 qf[4];
  #pragma unroll
  for (int d = 0; d < 4; ++d)
    qf[d] = *reinterpret_cast<const bf16x8*>(
        Qp + (size_t)(q0 + cl) * HD_ + d * 16 + hf * 8);
  __syncthreads();   // maskLds ready (only barrier in kernel)

  // per-lane fragment base pointers
  const u16* kbase = Kp  + (size_t)cl * HD_ + hf * 8;   // + kv*HD + d*16
  const u16* vbase = Vtp + (size_t)cl * S_  + hf * 8;   // + drow32*S + kv

  f32x16 oacc0 = {}, oacc1 = {};
  float dm = 0.f, lsum = 0.f;

  // prologue: K-frags for tile 0 (2 subs x 4 dsteps)
  bf16x8 kf[2][8];
  #pragma unroll
  for (int s = 0; s < 2; ++s)
    #pragma unroll
    for (int d = 0; d < 4; ++d)
      kf[0][s*4+d] = *reinterpret_cast<const bf16x8*>(kbase + (size_t)(s*32) * HD_ + d*16);

  for (int it = 0; it < 16; ++it) {
    #pragma unroll
    for (int h = 0; h < 2; ++h) {
      const int tt = 2*it + h;
      const int kv0 = tt * 64;
      // mask values for both subs (LDS, broadcast) — hoisted ahead of use
      float4 mk0[4], mk1[4];
      #pragma unroll
      for (int i = 0; i < 4; ++i) {
        mk0[i] = *reinterpret_cast<const float4*>(&maskLds[kv0 + 8*i + 4*hf]);
        mk1[i] = *reinterpret_cast<const float4*>(&maskLds[kv0 + 32 + 8*i + 4*hf]);
      }
      // V-frags for this tile (needed at PV, ~300cy away)
      bf16x8 vf[8];
      #pragma unroll
      for (int s = 0; s < 2; ++s) {
        vf[s*4+0] = *reinterpret_cast<const bf16x8*>(vbase + kv0 + s*32);
        vf[s*4+1] = *reinterpret_cast<const bf16x8*>(vbase + 32*(size_t)S_ + kv0 + s*32);
        vf[s*4+2] = *reinterpret_cast<const bf16x8*>(vbase + kv0 + s*32 + 16);
        vf[s*4+3] = *reinterpret_cast<const bf16x8*>(vbase + 32*(size_t)S_ + kv0 + s*32 + 16);
      }
      // ---- QK^T both subs (8 MFMA) ----
      f32x16 s0 = {}, s1 = {};
      __builtin_amdgcn_s_setprio(1);
      #pragma unroll
      for (int d = 0; d < 4; ++d)
        s0 = __builtin_amdgcn_mfma_f32_32x32x16_bf16(kf[h][d], qf[d], s0, 0, 0, 0);
      #pragma unroll
      for (int d = 0; d < 4; ++d)
        s1 = __builtin_amdgcn_mfma_f32_32x32x16_bf16(kf[h][4+d], qf[d], s1, 0, 0, 0);
      __builtin_amdgcn_s_setprio(0);
      // ---- prefetch next tile's K-frags (lands during SM/PV) ----
      {
        const int tn = (tt < 31) ? tt + 1 : 31;
        const u16* kn = kbase + (size_t)(tn * 64) * HD_;
        #pragma unroll
        for (int s = 0; s < 2; ++s)
          #pragma unroll
          for (int d = 0; d < 4; ++d)
            kf[h^1][s*4+d] = *reinterpret_cast<const bf16x8*>(kn + (size_t)(s*32) * HD_ + d*16);
      }
      bf16x8 pA, pB;
      // ---- SM0 + PV0 ----
      sm_pack(s0, mk0, dm, lsum, oacc0, oacc1, pA, pB);
      __builtin_amdgcn_s_setprio(1);
      oacc0 = __builtin_amdgcn_mfma_f32_32x32x16_bf16(vf[0], pA, oacc0, 0, 0, 0);
      oacc1 = __builtin_amdgcn_mfma_f32_32x32x16_bf16(vf[1], pA, oacc1, 0, 0, 0);
      oacc0 = __builtin_amdgcn_mfma_f32_32x32x16_bf16(vf[2], pB, oacc0, 0, 0, 0);
      oacc1 = __builtin_amdgcn_mfma_f32_32x32x16_bf16(vf[3], pB, oacc1, 0, 0, 0);
      __builtin_amdgcn_s_setprio(0);
      // ---- SM1 + PV1 ----
      sm_pack(s1, mk1, dm, lsum, oacc0, oacc1, pA, pB);
      __builtin_amdgcn_s_setprio(1);
      oacc0 = __builtin_amdgcn_mfma_f32_32x32x16_bf16(vf[4], pA, oacc0, 0, 0, 0);
      oacc1 = __builtin_amdgcn_mfma_f32_32x32x16_bf16(vf[5], pA, oacc1, 0, 0, 0);
      oacc0 = __builtin_amdgcn_mfma_f32_32x32x16_bf16(vf[6], pB, oacc0, 0, 0, 0);
      oacc1 = __builtin_amdgcn_mfma_f32_32x32x16_bf16(vf[7], pB, oacc1, 0, 0, 0);
      __builtin_amdgcn_s_setprio(0);
    }
  }

  // ---- epilogue: combine cross-half lsum once; O[q][d] = oacc / lsum ----
  lsum += __shfl_xor(lsum, 32);
  const float rinv = 1.0f / lsum;
  float* orow = out + ((size_t)bI * S_ + q0 + cl) * D_ + hI * HD_;
  #pragma unroll
  for (int jj = 0; jj < 4; ++jj) {
    float4 o0 = {oacc0[4*jj] * rinv, oacc0[4*jj+1] * rinv, oacc0[4*jj+2] * rinv, oacc0[4*jj+3] * rinv};
    float4 o1 = {oacc1[4*jj] * rinv, oacc1[4*jj+1] * rinv, oacc1[4*jj+2] * rinv, oacc1[4*jj+3] * rinv};
    *reinterpret_cast<float4*>(orow + 8*jj + 4*hf)      = o0;
    *reinterpret_cast<float4*>(orow + 32 + 8*jj + 4*hf) = o1;
  }
}

extern "C" void kernel_launch(void* const* d_in, const int* in_sizes, int n_in,
                              void* d_out, int out_size, void* d_ws, size_t ws_size,
                              hipStream_t stream) {
  const float* x     = (const float*)d_in[0];
  const float* mask  = (const float*)d_in[1];
  const float* gamma = (const float*)d_in[2];
  const float* beta  = (const float*)d_in[3];
  const float* Wq    = (const float*)d_in[4];
  const float* Wk    = (const float*)d_in[5];
  const float* Wv    = (const float*)d_in[6];
  float* out = (float*)d_out;

  char* ws = (char*)d_ws;
  u16* hbuf = (u16*)ws;                                        // 8 MiB
  u16* wt   = (u16*)(ws + (size_t)M_*D_*2);                    // 6 MiB
  u16* qkv  = (u16*)(ws + (size_t)M_*D_*2 + 3ull*D_*D_*2);     // 24 MiB

  hipLaunchKernelGGL(ln_kernel, dim3(M_), dim3(256), 0, stream, x, gamma, beta, hbuf);
  hipLaunchKernelGGL(wt_kernel, dim3(32, 32, 3), dim3(32, 8), 0, stream, Wq, Wk, Wv, wt);
  hipLaunchKernelGGL(qkv_gemm, dim3(8, 32, 3), dim3(256), 0, stream, hbuf, wt, qkv);
  hipLaunchKernelGGL(attn_kernel, dim3(512), dim3(256), 0, stream, qkv, mask, out);
}

// Round 5
// 106.855 us; speedup vs baseline: 1.5902x; 1.5902x over previous
//
#include <hip/hip_runtime.h>
#include <hip/hip_bf16.h>
#include <cstdint>

#define B_ 2
#define S_ 2048
#define D_ 1024
#define H_ 16
#define HD_ 64
#define M_ (B_*S_)   // 4096

#define LOG2E 1.4426950408889634f
#define C1_ (0.125f * LOG2E)   // 1/sqrt(64) * log2(e), folded into Q at GEMM epilogue

typedef unsigned short u16;
typedef __bf16 bf16x8 __attribute__((ext_vector_type(8)));
typedef u16 u16x8 __attribute__((ext_vector_type(8)));
typedef float f32x4 __attribute__((ext_vector_type(4)));
typedef float f32x16 __attribute__((ext_vector_type(16)));
typedef int i32x4 __attribute__((ext_vector_type(4)));

static __device__ __forceinline__ u16 f2bu(float f) {
  __bf16 b = (__bf16)f;
  return __builtin_bit_cast(unsigned short, b);
}

static __device__ __forceinline__ int cvtpk(float a, float b) {
  int r;
  asm("v_cvt_pk_bf16_f32 %0, %1, %2" : "=v"(r) : "v"(a), "v"(b));
  return r;
}
static __device__ __forceinline__ void plswap(int &x, int &y) {
  asm("v_permlane32_swap_b32 %0, %1" : "+v"(x), "+v"(y));
}

#define GLOAD16(g, l) __builtin_amdgcn_global_load_lds( \
    (__attribute__((address_space(1))) void*)(g), \
    (__attribute__((address_space(3))) void*)(l), 16, 0, 0)

// ---------------- LayerNorm: fp32 [4096][1024] -> bf16 h ----------------
__global__ __launch_bounds__(256) void ln_kernel(const float* __restrict__ x,
    const float* __restrict__ g, const float* __restrict__ be, u16* __restrict__ h) {
  const int row = blockIdx.x;
  const int t = threadIdx.x;
  float4 v = reinterpret_cast<const float4*>(x + (size_t)row * D_)[t];
  float s = v.x + v.y + v.z + v.w;
  float sq = v.x*v.x + v.y*v.y + v.z*v.z + v.w*v.w;
  #pragma unroll
  for (int off = 32; off >= 1; off >>= 1) {
    s  += __shfl_down(s, off);
    sq += __shfl_down(sq, off);
  }
  __shared__ float red[8];
  const int wave = t >> 6, lane = t & 63;
  if (lane == 0) { red[wave] = s; red[4 + wave] = sq; }
  __syncthreads();
  if (t == 0) {
    float ts = red[0]+red[1]+red[2]+red[3];
    float tq = red[4]+red[5]+red[6]+red[7];
    float mu = ts * (1.0f / D_);
    red[0] = mu;
    red[1] = rsqrtf(tq * (1.0f / D_) - mu*mu + 1e-5f);
  }
  __syncthreads();
  const float mu = red[0], rs = red[1];
  float4 gg = reinterpret_cast<const float4*>(g)[t];
  float4 bb = reinterpret_cast<const float4*>(be)[t];
  ushort4 o;
  o.x = f2bu((v.x - mu) * rs * gg.x + bb.x);
  o.y = f2bu((v.y - mu) * rs * gg.y + bb.y);
  o.z = f2bu((v.z - mu) * rs * gg.z + bb.z);
  o.w = f2bu((v.w - mu) * rs * gg.w + bb.w);
  reinterpret_cast<ushort4*>(h + (size_t)row * D_)[t] = o;
}

// ------------- Weight transpose+convert: W[k][n] fp32 -> Wt[n][k] bf16 -------------
__global__ __launch_bounds__(256) void wt_kernel(const float* __restrict__ W0,
    const float* __restrict__ W1, const float* __restrict__ W2, u16* __restrict__ wt) {
  const int z = blockIdx.z;
  const float* W = (z == 0) ? W0 : ((z == 1) ? W1 : W2);
  u16* out = wt + (size_t)z * D_ * D_;
  __shared__ float tile[32][33];
  const int n0 = blockIdx.x * 32, k0 = blockIdx.y * 32;
  const int tx = threadIdx.x, ty = threadIdx.y;
  #pragma unroll
  for (int j = 0; j < 4; ++j)
    tile[ty + 8*j][tx] = W[(size_t)(k0 + ty + 8*j) * D_ + n0 + tx];
  __syncthreads();
  #pragma unroll
  for (int j = 0; j < 4; ++j)
    out[(size_t)(n0 + ty + 8*j) * D_ + k0 + tx] = f2bu(tile[tx][ty + 8*j]);
}

// ------------- QKV GEMM: 128x128 tile, BK=32, T2-swizzled LDS -------------
// Q scaled by C1_ and stored [B,H,S,HD]; K [B,H,S,HD]; V TRANSPOSED [B,H,HD,S].
__global__ __launch_bounds__(256) void qkv_gemm(const u16* __restrict__ hbuf,
    const u16* __restrict__ wt, u16* __restrict__ qkv) {
  const int z = blockIdx.z;
  const u16* Bt = wt + (size_t)z * D_ * D_;
  u16* outp = qkv + (size_t)z * (B_*H_*S_*HD_);
  __shared__ __align__(16) u16 As[128 * 32];
  __shared__ __align__(16) u16 Bs[128 * 32];
  const int t = threadIdx.x, lane = t & 63, wave = t >> 6;
  const int row0 = blockIdx.y * 128, col0 = blockIdx.x * 128;
  const int wm = wave >> 1, wn = wave & 1;
  f32x4 acc[4][4] = {};
  const int schunk = (t & 3) ^ ((t >> 3) & 3);
  const u16* ag = hbuf + (size_t)(row0 + (t >> 2)) * D_ + schunk * 8;
  const u16* bg = Bt   + (size_t)(col0 + (t >> 2)) * D_ + schunk * 8;
  u16* lA = &As[wave * 512];
  u16* lB = &Bs[wave * 512];
  const char* Ac = (const char*)As;
  const char* Bc = (const char*)Bs;
  const int cbase = (((lane >> 4) ^ ((lane >> 1) & 3)) << 4);

  for (int k0 = 0; k0 < D_; k0 += 32) {
    GLOAD16(ag + k0,           lA);
    GLOAD16(ag + k0 + 64 * D_, lA + 2048);
    GLOAD16(bg + k0,           lB);
    GLOAD16(bg + k0 + 64 * D_, lB + 2048);
    __syncthreads();
    bf16x8 af[4], bfr[4];
    #pragma unroll
    for (int m = 0; m < 4; ++m)
      af[m] = *reinterpret_cast<const bf16x8*>(Ac + (wm*64 + m*16 + (lane & 15)) * 64 + cbase);
    #pragma unroll
    for (int n = 0; n < 4; ++n)
      bfr[n] = *reinterpret_cast<const bf16x8*>(Bc + (wn*64 + n*16 + (lane & 15)) * 64 + cbase);
    #pragma unroll
    for (int m = 0; m < 4; ++m) {
      #pragma unroll
      for (int n = 0; n < 4; ++n)
        acc[m][n] = __builtin_amdgcn_mfma_f32_16x16x32_bf16(af[m], bfr[n], acc[m][n], 0, 0, 0);
    }
    __syncthreads();
  }
  const float scl = (z == 0) ? C1_ : 1.0f;   // fold 1/sqrt(d)*log2e into Q
  #pragma unroll
  for (int m = 0; m < 4; ++m) {
    #pragma unroll
    for (int n = 0; n < 4; ++n) {
      const int gcol = col0 + wn*64 + n*16 + (lane & 15);
      const int hI = gcol >> 6, dI = gcol & 63;
      #pragma unroll
      for (int r = 0; r < 4; ++r) {
        const int grow = row0 + wm*64 + m*16 + (lane >> 4) * 4 + r;
        const int bI = grow >> 11, sI = grow & (S_ - 1);
        size_t idx;
        if (z == 2) idx = ((size_t)(bI * H_ + hI) * HD_ + dI) * S_ + sI;   // V transposed
        else        idx = ((size_t)(bI * H_ + hI) * S_ + sI) * HD_ + dI;
        outp[idx] = f2bu(acc[m][n][r] * scl);
      }
    }
  }
}

// ---- softmax + pack; defer-max, NO hot-path cross-lane ops (validated r4) ----
static __device__ __forceinline__ void sm_pack(
    const f32x16& s, const float4* __restrict__ mk,
    float& dm, float& lsum, f32x16& o0, f32x16& o1,
    bf16x8& pfA, bf16x8& pfB) {
  float zb[16];
  #pragma unroll
  for (int r = 0; r < 4; ++r) {
    zb[r]      = s[r]      + ((const float*)&mk[0])[r];
    zb[r + 4]  = s[r + 4]  + ((const float*)&mk[1])[r];
    zb[r + 8]  = s[r + 8]  + ((const float*)&mk[2])[r];
    zb[r + 12] = s[r + 12] + ((const float*)&mk[3])[r];
  }
  float a0 = fmaxf(fmaxf(zb[0], zb[1]), zb[2]);
  float a1 = fmaxf(fmaxf(zb[3], zb[4]), zb[5]);
  float a2 = fmaxf(fmaxf(zb[6], zb[7]), zb[8]);
  float a3 = fmaxf(fmaxf(zb[9], zb[10]), zb[11]);
  float a4 = fmaxf(fmaxf(zb[12], zb[13]), zb[14]);
  float tm = fmaxf(fmaxf(fmaxf(a0, a1), fmaxf(a2, a3)), fmaxf(a4, zb[15]));
  if (__builtin_expect(__any(tm > dm + 8.0f), 0)) {   // cold rescale
    float tp = fmaxf(tm, __shfl_xor(tm, 32));         // q-row pair max
    float dnew = fmaxf(dm, tp - 8.0f);
    float sf = __builtin_amdgcn_exp2f(dm - dnew);
    lsum *= sf; o0 = o0 * sf; o1 = o1 * sf; dm = dnew;
  }
  float p[16];
  #pragma unroll
  for (int r = 0; r < 16; ++r) p[r] = __builtin_amdgcn_exp2f(zb[r] - dm);
  float s01 = (p[0] + p[1]) + (p[2] + p[3]);
  float s23 = (p[4] + p[5]) + (p[6] + p[7]);
  float s45 = (p[8] + p[9]) + (p[10] + p[11]);
  float s67 = (p[12] + p[13]) + (p[14] + p[15]);
  lsum += (s01 + s23) + (s45 + s67);   // cross-half combine deferred to epilogue
  int pk01 = cvtpk(p[0], p[1]),   pk23 = cvtpk(p[2], p[3]);
  int pk45 = cvtpk(p[4], p[5]),   pk67 = cvtpk(p[6], p[7]);
  int pk89 = cvtpk(p[8], p[9]),   pkAB = cvtpk(p[10], p[11]);
  int pkCD = cvtpk(p[12], p[13]), pkEF = cvtpk(p[14], p[15]);
  plswap(pk01, pk45); plswap(pk23, pk67);
  plswap(pk89, pkCD); plswap(pkAB, pkEF);
  i32x4 c0 = {pk01, pk23, pk45, pk67};
  i32x4 c1 = {pk89, pkAB, pkCD, pkEF};
  pfA = __builtin_bit_cast(bf16x8, c0);
  pfB = __builtin_bit_cast(bf16x8, c1);
}

// ------------- Flash attention: LDS-staged, group-padded (bank-conflict-free) -------------
// 4 waves x 32 q; KVBLK=64 double-buffered. Each 8-row/1024B staged group at stride
// 1056B (+32B) -> rotates bank phase by 8 per group -> lanes {cl,cl+8,cl+16,cl+24}
// hit disjoint bank quads on fragment reads.
__global__ __launch_bounds__(256, 2) void attn_kernel(const u16* __restrict__ qkv,
    const float* __restrict__ mask, float* __restrict__ out) {
  const int bid = blockIdx.x;
  // bijective XCD map: plane p -> XCD (p&7); K/V of 4 planes (2MB) per XCD L2
  const int x = bid & 7, rr = bid >> 3;
  const int j = rr & 15;                    // q-tile (128 q)
  const int pidx = x + ((rr >> 4) << 3);    // plane 0..31 = b*16+h
  const int hI = pidx & 15, bI = pidx >> 4;
  const size_t plane = (size_t)pidx * (S_ * HD_);
  const u16* Qp  = qkv + plane;
  const u16* Kp  = qkv + (size_t)(B_*H_*S_*HD_) + plane;
  const u16* Vtp = qkv + 2*(size_t)(B_*H_*S_*HD_) + plane;   // [d][s]

  const int t = threadIdx.x, lane = t & 63, wave = t >> 6;
  const int cl = lane & 31, hf = lane >> 5;
  const int x7 = cl & 7;
  const int hx16 = (hf ^ x7) << 4;                 // read-side chunk XOR (bytes)
  const int rg = (cl >> 3) * 1056 + x7 * 128;      // group-padded row base (row cl)
  // row 32+cl -> rg + 4224

  __shared__ __align__(16) u16 KsBuf[2][4224];   // 8 groups x 1056B per buffer
  __shared__ __align__(16) u16 VsBuf[2][4224];
  __shared__ float maskLds[S_];

  // stage mask once: mask*log2e - 8 (defer-max offset baked in)
  #pragma unroll
  for (int i = 0; i < 2; ++i) {
    float4 mv = reinterpret_cast<const float4*>(mask + (size_t)bI * S_)[t + i*256];
    float4 sm = {mv.x * LOG2E - 8.0f, mv.y * LOG2E - 8.0f,
                 mv.z * LOG2E - 8.0f, mv.w * LOG2E - 8.0f};
    reinterpret_cast<float4*>(maskLds)[t + i*256] = sm;
  }

  const int q0 = j * 128 + wave * 32;
  bf16x8 qf[4];   // Q pre-scaled by C1_ at GEMM epilogue
  #pragma unroll
  for (int d = 0; d < 4; ++d)
    qf[d] = *reinterpret_cast<const bf16x8*>(
        Qp + (size_t)(q0 + cl) * HD_ + d * 16 + hf * 8);

  // staging: pre-swizzled source (slot s of row r holds global chunk s^(r&7)), linear dest
  const int sr = t >> 3;                                     // row 0..31
  const int scol = ((t & 7) ^ ((t >> 3) & 7)) << 3;          // element col
  const u16* kSrc = Kp  + (size_t)sr * HD_ + scol;
  const u16* vSrc = Vtp + (size_t)sr * S_  + scol;
  const int dst0 = wave * 528, dst1 = (4 + wave) * 528;      // u16 offsets (1056B groups)

  f32x16 oacc0 = {}, oacc1 = {};
  float dm = 0.f, lsum = 0.f;

  GLOAD16(kSrc,                   &KsBuf[0][dst0]);
  GLOAD16(kSrc + 32 * HD_,        &KsBuf[0][dst1]);
  GLOAD16(vSrc,                   &VsBuf[0][dst0]);
  GLOAD16(vSrc + 32 * (size_t)S_, &VsBuf[0][dst1]);
  int cur = 0;

  for (int kv0 = 0; kv0 < S_; kv0 += 64) {
    __syncthreads();   // buf[cur] ready (drains vmcnt)
    if (kv0 + 64 < S_) {
      const u16* kn = kSrc + (size_t)(kv0 + 64) * HD_;
      const u16* vn = vSrc + (kv0 + 64);
      GLOAD16(kn,                   &KsBuf[cur ^ 1][dst0]);
      GLOAD16(kn + 32 * HD_,        &KsBuf[cur ^ 1][dst1]);
      GLOAD16(vn,                   &VsBuf[cur ^ 1][dst0]);
      GLOAD16(vn + 32 * (size_t)S_, &VsBuf[cur ^ 1][dst1]);
    }
    const char* Ks = (const char*)KsBuf[cur];
    const char* Vs = (const char*)VsBuf[cur];

    // ---- K fragments (8 x ds_read_b128, conflict-free) ----
    bf16x8 k0[4], k1[4];
    #pragma unroll
    for (int d = 0; d < 4; ++d) {
      k0[d] = *reinterpret_cast<const bf16x8*>(Ks + rg + ((d << 5) ^ hx16));
      k1[d] = *reinterpret_cast<const bf16x8*>(Ks + rg + 4224 + ((d << 5) ^ hx16));
    }
    // mask values (LDS broadcast), hoisted
    float4 mk0[4], mk1[4];
    #pragma unroll
    for (int i = 0; i < 4; ++i) {
      mk0[i] = *reinterpret_cast<const float4*>(&maskLds[kv0 + 8*i + 4*hf]);
      mk1[i] = *reinterpret_cast<const float4*>(&maskLds[kv0 + 32 + 8*i + 4*hf]);
    }
    // ---- QK^T both subs (8 MFMA) ----
    f32x16 s0 = {}, s1 = {};
    __builtin_amdgcn_s_setprio(1);
    #pragma unroll
    for (int d = 0; d < 4; ++d)
      s0 = __builtin_amdgcn_mfma_f32_32x32x16_bf16(k0[d], qf[d], s0, 0, 0, 0);
    #pragma unroll
    for (int d = 0; d < 4; ++d)
      s1 = __builtin_amdgcn_mfma_f32_32x32x16_bf16(k1[d], qf[d], s1, 0, 0, 0);
    __builtin_amdgcn_s_setprio(0);

    // ---- V fragments sub0 (hoisted: LDS latency hides under softmax VALU) ----
    bf16x8 v0[4], v1[4];
    v0[0] = *reinterpret_cast<const bf16x8*>(Vs + rg + (0 ^ hx16));
    v0[1] = *reinterpret_cast<const bf16x8*>(Vs + rg + 4224 + (0 ^ hx16));
    v0[2] = *reinterpret_cast<const bf16x8*>(Vs + rg + (32 ^ hx16));
    v0[3] = *reinterpret_cast<const bf16x8*>(Vs + rg + 4224 + (32 ^ hx16));
    bf16x8 pA, pB;
    sm_pack(s0, mk0, dm, lsum, oacc0, oacc1, pA, pB);
    __builtin_amdgcn_s_setprio(1);
    oacc0 = __builtin_amdgcn_mfma_f32_32x32x16_bf16(v0[0], pA, oacc0, 0, 0, 0);
    oacc1 = __builtin_amdgcn_mfma_f32_32x32x16_bf16(v0[1], pA, oacc1, 0, 0, 0);
    oacc0 = __builtin_amdgcn_mfma_f32_32x32x16_bf16(v0[2], pB, oacc0, 0, 0, 0);
    oacc1 = __builtin_amdgcn_mfma_f32_32x32x16_bf16(v0[3], pB, oacc1, 0, 0, 0);
    __builtin_amdgcn_s_setprio(0);
    // ---- V fragments sub1 + SM1 + PV1 ----
    v1[0] = *reinterpret_cast<const bf16x8*>(Vs + rg + (64 ^ hx16));
    v1[1] = *reinterpret_cast<const bf16x8*>(Vs + rg + 4224 + (64 ^ hx16));
    v1[2] = *reinterpret_cast<const bf16x8*>(Vs + rg + (96 ^ hx16));
    v1[3] = *reinterpret_cast<const bf16x8*>(Vs + rg + 4224 + (96 ^ hx16));
    sm_pack(s1, mk1, dm, lsum, oacc0, oacc1, pA, pB);
    __builtin_amdgcn_s_setprio(1);
    oacc0 = __builtin_amdgcn_mfma_f32_32x32x16_bf16(v1[0], pA, oacc0, 0, 0, 0);
    oacc1 = __builtin_amdgcn_mfma_f32_32x32x16_bf16(v1[1], pA, oacc1, 0, 0, 0);
    oacc0 = __builtin_amdgcn_mfma_f32_32x32x16_bf16(v1[2], pB, oacc0, 0, 0, 0);
    oacc1 = __builtin_amdgcn_mfma_f32_32x32x16_bf16(v1[3], pB, oacc1, 0, 0, 0);
    __builtin_amdgcn_s_setprio(0);
    cur ^= 1;
  }

  // ---- epilogue ----
  lsum += __shfl_xor(lsum, 32);
  const float rinv = 1.0f / lsum;
  float* orow = out + ((size_t)bI * S_ + q0 + cl) * D_ + hI * HD_;
  #pragma unroll
  for (int jj = 0; jj < 4; ++jj) {
    float4 o0 = {oacc0[4*jj] * rinv, oacc0[4*jj+1] * rinv, oacc0[4*jj+2] * rinv, oacc0[4*jj+3] * rinv};
    float4 o1 = {oacc1[4*jj] * rinv, oacc1[4*jj+1] * rinv, oacc1[4*jj+2] * rinv, oacc1[4*jj+3] * rinv};
    *reinterpret_cast<float4*>(orow + 8*jj + 4*hf)      = o0;
    *reinterpret_cast<float4*>(orow + 32 + 8*jj + 4*hf) = o1;
  }
}

extern "C" void kernel_launch(void* const* d_in, const int* in_sizes, int n_in,
                              void* d_out, int out_size, void* d_ws, size_t ws_size,
                              hipStream_t stream) {
  const float* x     = (const float*)d_in[0];
  const float* mask  = (const float*)d_in[1];
  const float* gamma = (const float*)d_in[2];
  const float* beta  = (const float*)d_in[3];
  const float* Wq    = (const float*)d_in[4];
  const float* Wk    = (const float*)d_in[5];
  const float* Wv    = (const float*)d_in[6];
  float* out = (float*)d_out;

  char* ws = (char*)d_ws;
  u16* hbuf = (u16*)ws;                                        // 8 MiB
  u16* wt   = (u16*)(ws + (size_t)M_*D_*2);                    // 6 MiB
  u16* qkv  = (u16*)(ws + (size_t)M_*D_*2 + 3ull*D_*D_*2);     // 24 MiB

  hipLaunchKernelGGL(ln_kernel, dim3(M_), dim3(256), 0, stream, x, gamma, beta, hbuf);
  hipLaunchKernelGGL(wt_kernel, dim3(32, 32, 3), dim3(32, 8), 0, stream, Wq, Wk, Wv, wt);
  hipLaunchKernelGGL(qkv_gemm, dim3(8, 32, 3), dim3(256), 0, stream, hbuf, wt, qkv);
  hipLaunchKernelGGL(attn_kernel, dim3(512), dim3(256), 0, stream, qkv, mask, out);
}